// Round 1
// baseline (1816.253 us; speedup 1.0000x reference)
//
#include <hip/hip_runtime.h>
#include <hip/hip_bf16.h>

#define M_DIM 16384
#define N_DIM 8192
#define K_DIM 4096

typedef __attribute__((ext_vector_type(4))) float f32x4;
typedef __attribute__((ext_vector_type(8))) __bf16 bf16x8;
typedef __attribute__((ext_vector_type(4))) unsigned short u16x4;

static __device__ __forceinline__ unsigned short f2bf(float f) {
  __bf16 h = (__bf16)f;
  return __builtin_bit_cast(unsigned short, h);
}

static __device__ __forceinline__ void gl_lds16(const void* g, void* l) {
  __builtin_amdgcn_global_load_lds(
      (const __attribute__((address_space(1))) unsigned int*)g,
      (__attribute__((address_space(3))) unsigned int*)l,
      16, 0, 0);
}

// ---- prep: A [M][K] f32 -> bf16 (same layout) ----
__global__ void k_convert_a(const float* __restrict__ a, unsigned short* __restrict__ o) {
  const size_t n8 = (size_t)M_DIM * K_DIM / 8;
  for (size_t i = (size_t)blockIdx.x * blockDim.x + threadIdx.x; i < n8;
       i += (size_t)gridDim.x * blockDim.x) {
    const f32x4* p = (const f32x4*)(a + i * 8);
    f32x4 v0 = p[0];
    f32x4 v1 = p[1];
    u16x4 r0, r1;
#pragma unroll
    for (int j = 0; j < 4; ++j) { r0[j] = f2bf(v0[j]); r1[j] = f2bf(v1[j]); }
    *(u16x4*)(o + i * 8) = r0;
    *(u16x4*)(o + i * 8 + 4) = r1;
  }
}

// ---- prep: W [K][N] f32 -> Wt [N][K] bf16 (transpose + convert) ----
__global__ void k_convert_w_t(const float* __restrict__ w, unsigned short* __restrict__ wt) {
  __shared__ float tile[64][65];
  const int bk = blockIdx.y * 64;  // K block
  const int bn = blockIdx.x * 64;  // N block
  const int t = threadIdx.x;       // 256
  const int c4 = (t & 15) * 4;
  const int r = t >> 4;            // 0..15
#pragma unroll
  for (int p = 0; p < 4; ++p) {
    const int row = r + p * 16;  // k within tile
    f32x4 v = *(const f32x4*)&w[(size_t)(bk + row) * N_DIM + bn + c4];
    tile[row][c4 + 0] = v[0];
    tile[row][c4 + 1] = v[1];
    tile[row][c4 + 2] = v[2];
    tile[row][c4 + 3] = v[3];
  }
  __syncthreads();
#pragma unroll
  for (int p = 0; p < 4; ++p) {
    const int c = r + p * 16;  // n within tile
    u16x4 o;
#pragma unroll
    for (int j = 0; j < 4; ++j) o[j] = f2bf(tile[c4 + j][c]);
    *(u16x4*)&wt[(size_t)(bn + c) * K_DIM + bk + c4] = o;
  }
}

// ---- main GEMM: C = A(bf16)[M][K] · Bt(bf16)[N][K]^T + bias, m97 structure ----
__global__ __launch_bounds__(256) void k_gemm_bf16(
    const unsigned short* __restrict__ A, const unsigned short* __restrict__ Bt,
    const float* __restrict__ bias, float* __restrict__ C) {
  __shared__ __align__(16) unsigned short As[128 * 64];
  __shared__ __align__(16) unsigned short Bs[128 * 64];

  const int tid = threadIdx.x;
  const int lane = tid & 63;
  const int wave = tid >> 6;
  const int wr = wave >> 1;  // 0..1
  const int wc = wave & 1;   // 0..1

  // XCD-aware bijective swizzle; nwg = 8192 (divisible by 8)
  const int bid = blockIdx.x;
  const int swz = (bid & 7) * (8192 / 8) + (bid >> 3);
  const int brow = (swz >> 6) * 128;  // 64 col-tiles per row-panel
  const int bcol = (swz & 63) * 128;

  // staging: each thread loads 16B; 4 iters cover 128 rows x 64 k (bf16)
  const int ldr = tid >> 3;        // 0..31 (row within 32-row group)
  const int ldk = (tid & 7) * 8;   // k offset in elements

  const unsigned short* ag = A + (size_t)(brow + ldr) * K_DIM + ldk;
  const unsigned short* bg = Bt + (size_t)(bcol + ldr) * K_DIM + ldk;

  f32x4 acc[4][4] = {};

  const int fr = lane & 15;        // fragment row/col
  const int fk = (lane >> 4) * 8;  // fragment k offset

  for (int ks = 0; ks < K_DIM; ks += 64) {
#pragma unroll
    for (int it = 0; it < 4; ++it) {
      gl_lds16(ag + (size_t)(it * 32) * K_DIM + ks, As + (it * 256 + tid) * 8);
      gl_lds16(bg + (size_t)(it * 32) * K_DIM + ks, Bs + (it * 256 + tid) * 8);
    }
    __syncthreads();  // drains vmcnt(0) then barrier
#pragma unroll
    for (int kk = 0; kk < 2; ++kk) {
      bf16x8 av[4], bv[4];
#pragma unroll
      for (int m = 0; m < 4; ++m)
        av[m] = *(const bf16x8*)&As[(wr * 64 + m * 16 + fr) * 64 + kk * 32 + fk];
#pragma unroll
      for (int n = 0; n < 4; ++n)
        bv[n] = *(const bf16x8*)&Bs[(wc * 64 + n * 16 + fr) * 64 + kk * 32 + fk];
#pragma unroll
      for (int m = 0; m < 4; ++m)
#pragma unroll
        for (int n = 0; n < 4; ++n)
          acc[m][n] = __builtin_amdgcn_mfma_f32_16x16x32_bf16(av[m], bv[n], acc[m][n], 0, 0, 0);
    }
    __syncthreads();
  }

  // epilogue: C/D layout col = lane&15, row = (lane>>4)*4 + j  [m89-verified]
#pragma unroll
  for (int n = 0; n < 4; ++n) {
    const int col = bcol + wc * 64 + n * 16 + fr;
    const float bb = bias[col];
#pragma unroll
    for (int m = 0; m < 4; ++m) {
      const int row0 = brow + wr * 64 + m * 16 + (lane >> 4) * 4;
#pragma unroll
      for (int j = 0; j < 4; ++j)
        C[(size_t)(row0 + j) * N_DIM + col] = acc[m][n][j] + bb;
    }
  }
}

// ---- fallback (only if ws too small): fp32 LDS-tiled GEMM ----
__global__ __launch_bounds__(256) void k_gemm_f32(
    const float* __restrict__ A, const float* __restrict__ W,
    const float* __restrict__ bias, float* __restrict__ C) {
  __shared__ float As[64][17];
  __shared__ float Ws[16][64];
  const int tid = threadIdx.x;
  const int tx = tid & 15, ty = tid >> 4;
  const int brow = blockIdx.y * 64, bcol = blockIdx.x * 64;
  float acc[4][4] = {};
  for (int ks = 0; ks < K_DIM; ks += 16) {
    {
      const int m = tid >> 2, k = (tid & 3) * 4;
      f32x4 v = *(const f32x4*)&A[(size_t)(brow + m) * K_DIM + ks + k];
      As[m][k] = v[0]; As[m][k + 1] = v[1]; As[m][k + 2] = v[2]; As[m][k + 3] = v[3];
    }
    {
      const int k = tid >> 4, n = (tid & 15) * 4;
      *(f32x4*)&Ws[k][n] = *(const f32x4*)&W[(size_t)(ks + k) * N_DIM + bcol + n];
    }
    __syncthreads();
#pragma unroll
    for (int k = 0; k < 16; ++k) {
      float av[4], bv[4];
#pragma unroll
      for (int i = 0; i < 4; ++i) av[i] = As[ty * 4 + i][k];
#pragma unroll
      for (int j = 0; j < 4; ++j) bv[j] = Ws[k][tx * 4 + j];
#pragma unroll
      for (int i = 0; i < 4; ++i)
#pragma unroll
        for (int j = 0; j < 4; ++j) acc[i][j] += av[i] * bv[j];
    }
    __syncthreads();
  }
#pragma unroll
  for (int i = 0; i < 4; ++i) {
    const int row = brow + ty * 4 + i;
#pragma unroll
    for (int j = 0; j < 4; ++j) {
      const int col = bcol + tx * 4 + j;
      C[(size_t)row * N_DIM + col] = acc[i][j] + bias[col];
    }
  }
}

extern "C" void kernel_launch(void* const* d_in, const int* in_sizes, int n_in,
                              void* d_out, int out_size, void* d_ws, size_t ws_size,
                              hipStream_t stream) {
  const float* inp = (const float*)d_in[0];   // [16384, 4096]
  const float* w = (const float*)d_in[1];     // [4096, 8192]
  const float* bias = (const float*)d_in[2];  // [8192]
  float* out = (float*)d_out;                 // [16384, 8192]

  const size_t needA = (size_t)M_DIM * K_DIM * sizeof(unsigned short);  // 128 MB
  const size_t needW = (size_t)N_DIM * K_DIM * sizeof(unsigned short);  // 64 MB

  if (ws_size >= needA + needW) {
    unsigned short* Abf = (unsigned short*)d_ws;
    unsigned short* Wtb = (unsigned short*)((char*)d_ws + needA);
    k_convert_a<<<2048, 256, 0, stream>>>(inp, Abf);
    k_convert_w_t<<<dim3(N_DIM / 64, K_DIM / 64), 256, 0, stream>>>(w, Wtb);
    k_gemm_bf16<<<(M_DIM / 128) * (N_DIM / 128), 256, 0, stream>>>(Abf, Wtb, bias, out);
  } else {
    k_gemm_f32<<<dim3(N_DIM / 64, M_DIM / 64), 256, 0, stream>>>(inp, w, bias, out);
  }
}

// Round 2
// 1178.840 us; speedup vs baseline: 1.5407x; 1.5407x over previous
//
#include <hip/hip_runtime.h>
#include <hip/hip_bf16.h>

#define M_DIM 16384
#define N_DIM 8192
#define K_DIM 4096
#define NT (K_DIM / 64)  // 64 K-tiles

typedef __attribute__((ext_vector_type(4))) float f32x4;
typedef __attribute__((ext_vector_type(8))) __bf16 bf16x8;
typedef __attribute__((ext_vector_type(4))) unsigned short u16x4;

static __device__ __forceinline__ unsigned short f2bf(float f) {
  __bf16 h = (__bf16)f;
  return __builtin_bit_cast(unsigned short, h);
}

static __device__ __forceinline__ void gl_lds16(const unsigned short* g, unsigned short* l) {
  __builtin_amdgcn_global_load_lds(
      (const __attribute__((address_space(1))) unsigned int*)g,
      (__attribute__((address_space(3))) unsigned int*)l, 16, 0, 0);
}

// ---- prep: A [M][K] f32 -> bf16 (same layout) ----
__global__ void k_convert_a(const float* __restrict__ a, unsigned short* __restrict__ o) {
  const size_t n8 = (size_t)M_DIM * K_DIM / 8;
  for (size_t i = (size_t)blockIdx.x * blockDim.x + threadIdx.x; i < n8;
       i += (size_t)gridDim.x * blockDim.x) {
    const f32x4* p = (const f32x4*)(a + i * 8);
    f32x4 v0 = p[0];
    f32x4 v1 = p[1];
    u16x4 r0, r1;
#pragma unroll
    for (int j = 0; j < 4; ++j) { r0[j] = f2bf(v0[j]); r1[j] = f2bf(v1[j]); }
    *(u16x4*)(o + i * 8) = r0;
    *(u16x4*)(o + i * 8 + 4) = r1;
  }
}

// ---- prep: W [K][N] f32 -> Wt [N][K] bf16 (transpose + convert) ----
__global__ void k_convert_w_t(const float* __restrict__ w, unsigned short* __restrict__ wt) {
  __shared__ float tile[64][65];
  const int bk = blockIdx.y * 64;
  const int bn = blockIdx.x * 64;
  const int t = threadIdx.x;  // 256
  const int c4 = (t & 15) * 4;
  const int r = t >> 4;
#pragma unroll
  for (int p = 0; p < 4; ++p) {
    const int row = r + p * 16;
    f32x4 v = *(const f32x4*)&w[(size_t)(bk + row) * N_DIM + bn + c4];
    tile[row][c4 + 0] = v[0];
    tile[row][c4 + 1] = v[1];
    tile[row][c4 + 2] = v[2];
    tile[row][c4 + 3] = v[3];
  }
  __syncthreads();
#pragma unroll
  for (int p = 0; p < 4; ++p) {
    const int c = r + p * 16;
    u16x4 o;
#pragma unroll
    for (int j = 0; j < 4; ++j) o[j] = f2bf(tile[c4 + j][c]);
    *(u16x4*)&wt[(size_t)(bn + c) * K_DIM + bk + c4] = o;
  }
}

// ---- main GEMM: 256x256 tile, BK=64, 8-phase-per-2-tiles schedule ----
// LDS: 2 buffers x 4 regions {A0,A1,B0,B1} x 16KB = 128 KB.
// T2 swizzle: physical kelem = logical kelem ^ ((row&7)<<3)  (involution, 16B granules)
// applied on the pre-swizzled global SOURCE of global_load_lds and on ds_read addrs.
__global__ __launch_bounds__(512, 2) void k_gemm_8ph(
    const unsigned short* __restrict__ A, const unsigned short* __restrict__ Bt,
    const float* __restrict__ bias, float* __restrict__ C) {
  __shared__ __align__(16) unsigned short S[65536];  // 128 KB

  const int tid = threadIdx.x;
  const int lane = tid & 63;
  const int wave = tid >> 6;  // 0..7
  const int wm = wave >> 2;   // 0..1 -> A half / 128-row block
  const int wn = wave & 3;    // 0..3 -> 64-col block
  const int fr = lane & 15;
  const int hi = lane >> 4;   // 0..3

  // T1: XCD-aware bijective swizzle. 2048 blocks, 2048%8==0.
  // Each XCD gets a 4-wide column super-panel; m varies fastest within chunk.
  const int bid = blockIdx.x;
  const int swz = (bid & 7) * 256 + (bid >> 3);
  const int local = swz & 255;
  const int tm = local & 63;                       // 0..63  (M/256)
  const int tn = (swz >> 8) * 4 + (local >> 6);    // 0..31  (N/256)
  const int brow = tm * 256;
  const int bcol = tn * 256;

  // staging source (per-lane, pre-swizzled k). Each thread: 16B per gl_lds.
  const int srow = tid >> 3;                                   // 0..63
  const int skel = ((tid & 7) * 8) ^ ((srow & 7) << 3);        // swizzled k-elem
  const unsigned short* aSrc = A + (size_t)(brow + srow) * K_DIM + skel;
  const unsigned short* bSrc = Bt + (size_t)(bcol + srow) * K_DIM + skel;
  unsigned short* const Sb0 = S;

  // stage half h of tile tt for A (regions 0,1) / B (regions 2,3) of buf tt&1.
  // LDS dest is LINEAR: region + i*4096 + tid*8 elems (wave-uniform base + lane*16B).
#define STAGE_A(h, tt)                                                                   \
  do {                                                                                   \
    unsigned short* d = Sb0 + ((tt)&1) * 32768 + (h)*8192 + tid * 8;                     \
    const unsigned short* g = aSrc + (size_t)((h)*128) * K_DIM + (size_t)(tt)*64;        \
    gl_lds16(g, d);                                                                      \
    gl_lds16(g + (size_t)64 * K_DIM, d + 4096);                                          \
  } while (0)
#define STAGE_B(h, tt)                                                                   \
  do {                                                                                   \
    unsigned short* d = Sb0 + ((tt)&1) * 32768 + (2 + (h)) * 8192 + tid * 8;             \
    const unsigned short* g = bSrc + (size_t)((h)*128) * K_DIM + (size_t)(tt)*64;        \
    gl_lds16(g, d);                                                                      \
    gl_lds16(g + (size_t)64 * K_DIM, d + 4096);                                          \
  } while (0)

  // frag-read swizzled k offsets (elements, 8-elem granules)
  const int swk0 = (hi * 8) ^ ((fr & 7) << 3);         // kk=0
  const int swk1 = (32 + hi * 8) ^ ((fr & 7) << 3);    // kk=1

  f32x4 acc[8][4] = {};

  // ---- prologue: tile0 full + tile1 A halves; wait tile0 landed (4 loads in flight) ----
  STAGE_A(0, 0); STAGE_A(1, 0); STAGE_B(0, 0); STAGE_B(1, 0);
  STAGE_A(0, 1); STAGE_A(1, 1);
  asm volatile("s_waitcnt vmcnt(4)" ::: "memory");
  asm volatile("s_barrier" ::: "memory");

  for (int t = 0; t < NT; ++t) {
    const int X = t & 1;
    const unsigned short* Sa = Sb0 + X * 32768 + wm * 8192 + fr * 64;
    const unsigned short* Sb = Sb0 + X * 32768 + (2 + (wn >> 1)) * 8192 + ((wn & 1) * 64 + fr) * 64;
    bf16x8 a0[8], a1[8], b0[4], b1[4];

    // ---------- phase 1: read kk0 frags; stage B0(t+1); MFMA q0 (m0-3,kk0) ----------
#pragma unroll
    for (int n = 0; n < 4; ++n) b0[n] = *(const bf16x8*)(Sb + n * 1024 + swk0);
#pragma unroll
    for (int m = 0; m < 8; ++m) a0[m] = *(const bf16x8*)(Sa + m * 1024 + swk0);
    if (t + 1 < NT) STAGE_B(0, t + 1);
    asm volatile("s_barrier" ::: "memory");
    __builtin_amdgcn_s_setprio(1);
#pragma unroll
    for (int m = 0; m < 4; ++m)
#pragma unroll
      for (int n = 0; n < 4; ++n)
        acc[m][n] = __builtin_amdgcn_mfma_f32_16x16x32_bf16(a0[m], b0[n], acc[m][n], 0, 0, 0);
    __builtin_amdgcn_s_setprio(0);
    asm volatile("s_barrier" ::: "memory");

    // ---------- phase 2: read kk1 frags; stage B1(t+1); MFMA q1 (m4-7,kk0) ----------
#pragma unroll
    for (int m = 0; m < 8; ++m) a1[m] = *(const bf16x8*)(Sa + m * 1024 + swk1);
#pragma unroll
    for (int n = 0; n < 4; ++n) b1[n] = *(const bf16x8*)(Sb + n * 1024 + swk1);
    if (t + 1 < NT) STAGE_B(1, t + 1);
    asm volatile("s_barrier" ::: "memory");
    __builtin_amdgcn_s_setprio(1);
#pragma unroll
    for (int m = 4; m < 8; ++m)
#pragma unroll
      for (int n = 0; n < 4; ++n)
        acc[m][n] = __builtin_amdgcn_mfma_f32_16x16x32_bf16(a0[m], b0[n], acc[m][n], 0, 0, 0);
    __builtin_amdgcn_s_setprio(0);
    // all reads of buf X serviced before this barrier -> re-staging X later is race-free
    asm volatile("s_waitcnt lgkmcnt(0)" ::: "memory");
    asm volatile("s_barrier" ::: "memory");

    // ---------- phase 3: stage A0(t+2); MFMA q2 (m0-3,kk1) ----------
    if (t + 2 < NT) STAGE_A(0, t + 2);
    asm volatile("s_barrier" ::: "memory");
    __builtin_amdgcn_s_setprio(1);
#pragma unroll
    for (int m = 0; m < 4; ++m)
#pragma unroll
      for (int n = 0; n < 4; ++n)
        acc[m][n] = __builtin_amdgcn_mfma_f32_16x16x32_bf16(a1[m], b1[n], acc[m][n], 0, 0, 0);
    __builtin_amdgcn_s_setprio(0);
    asm volatile("s_barrier" ::: "memory");

    // ---------- phase 4: stage A1(t+2); MFMA q3 (m4-7,kk1); counted vmcnt ----------
    if (t + 2 < NT) STAGE_A(1, t + 2);
    asm volatile("s_barrier" ::: "memory");
    __builtin_amdgcn_s_setprio(1);
#pragma unroll
    for (int m = 4; m < 8; ++m)
#pragma unroll
      for (int n = 0; n < 4; ++n)
        acc[m][n] = __builtin_amdgcn_mfma_f32_16x16x32_bf16(a1[m], b1[n], acc[m][n], 0, 0, 0);
    __builtin_amdgcn_s_setprio(0);
    // steady state: keep this group's 2 A-half-tiles (4 loads) in flight; drain B(t+1)
    if (t + 2 < NT)
      asm volatile("s_waitcnt vmcnt(4)" ::: "memory");
    else
      asm volatile("s_waitcnt vmcnt(0)" ::: "memory");
    asm volatile("s_barrier" ::: "memory");
  }
#undef STAGE_A
#undef STAGE_B

  // ---- epilogue: C/D layout col = lane&15, row = (lane>>4)*4 + j ----
#pragma unroll
  for (int n = 0; n < 4; ++n) {
    const int col = bcol + wn * 64 + n * 16 + fr;
    const float bb = bias[col];
#pragma unroll
    for (int m = 0; m < 8; ++m) {
      const int row0 = brow + wm * 128 + m * 16 + hi * 4;
#pragma unroll
      for (int j = 0; j < 4; ++j)
        C[(size_t)(row0 + j) * N_DIM + col] = acc[m][n][j] + bb;
    }
  }
}

// ---- fallback (only if ws too small): fp32 LDS-tiled GEMM ----
__global__ __launch_bounds__(256) void k_gemm_f32(
    const float* __restrict__ A, const float* __restrict__ W,
    const float* __restrict__ bias, float* __restrict__ C) {
  __shared__ float As[64][17];
  __shared__ float Ws[16][64];
  const int tid = threadIdx.x;
  const int tx = tid & 15, ty = tid >> 4;
  const int brow = blockIdx.y * 64, bcol = blockIdx.x * 64;
  float acc[4][4] = {};
  for (int ks = 0; ks < K_DIM; ks += 16) {
    {
      const int m = tid >> 2, k = (tid & 3) * 4;
      f32x4 v = *(const f32x4*)&A[(size_t)(brow + m) * K_DIM + ks + k];
      As[m][k] = v[0]; As[m][k + 1] = v[1]; As[m][k + 2] = v[2]; As[m][k + 3] = v[3];
    }
    {
      const int k = tid >> 4, n = (tid & 15) * 4;
      *(f32x4*)&Ws[k][n] = *(const f32x4*)&W[(size_t)(ks + k) * N_DIM + bcol + n];
    }
    __syncthreads();
#pragma unroll
    for (int k = 0; k < 16; ++k) {
      float av[4], bv[4];
#pragma unroll
      for (int i = 0; i < 4; ++i) av[i] = As[ty * 4 + i][k];
#pragma unroll
      for (int j = 0; j < 4; ++j) bv[j] = Ws[k][tx * 4 + j];
#pragma unroll
      for (int i = 0; i < 4; ++i)
#pragma unroll
        for (int j = 0; j < 4; ++j) acc[i][j] += av[i] * bv[j];
    }
    __syncthreads();
  }
#pragma unroll
  for (int i = 0; i < 4; ++i) {
    const int row = brow + ty * 4 + i;
#pragma unroll
    for (int j = 0; j < 4; ++j) {
      const int col = bcol + tx * 4 + j;
      C[(size_t)row * N_DIM + col] = acc[i][j] + bias[col];
    }
  }
}

extern "C" void kernel_launch(void* const* d_in, const int* in_sizes, int n_in,
                              void* d_out, int out_size, void* d_ws, size_t ws_size,
                              hipStream_t stream) {
  const float* inp = (const float*)d_in[0];   // [16384, 4096]
  const float* w = (const float*)d_in[1];     // [4096, 8192]
  const float* bias = (const float*)d_in[2];  // [8192]
  float* out = (float*)d_out;                 // [16384, 8192]

  const size_t needA = (size_t)M_DIM * K_DIM * sizeof(unsigned short);  // 128 MB
  const size_t needW = (size_t)N_DIM * K_DIM * sizeof(unsigned short);  // 64 MB

  if (ws_size >= needA + needW) {
    unsigned short* Abf = (unsigned short*)d_ws;
    unsigned short* Wtb = (unsigned short*)((char*)d_ws + needA);
    k_convert_a<<<2048, 256, 0, stream>>>(inp, Abf);
    k_convert_w_t<<<dim3(N_DIM / 64, K_DIM / 64), 256, 0, stream>>>(w, Wtb);
    k_gemm_8ph<<<(M_DIM / 256) * (N_DIM / 256), 512, 0, stream>>>(Abf, Wtb, bias, out);
  } else {
    k_gemm_f32<<<dim3(N_DIM / 64, M_DIM / 64), 256, 0, stream>>>(inp, w, bias, out);
  }
}

// Round 3
// 1154.726 us; speedup vs baseline: 1.5729x; 1.0209x over previous
//
#include <hip/hip_runtime.h>
#include <hip/hip_bf16.h>

#define M_DIM 16384
#define N_DIM 8192
#define K_DIM 4096
#define NT (K_DIM / 64)  // 64 K-tiles, 32 iterations of 2 tiles

typedef __attribute__((ext_vector_type(4))) float f32x4;
typedef __attribute__((ext_vector_type(8))) __bf16 bf16x8;
typedef __attribute__((ext_vector_type(4))) unsigned short u16x4;

static __device__ __forceinline__ unsigned short f2bf(float f) {
  __bf16 h = (__bf16)f;
  return __builtin_bit_cast(unsigned short, h);
}

static __device__ __forceinline__ void gl_lds16(const unsigned short* g, unsigned short* l) {
  __builtin_amdgcn_global_load_lds(
      (const __attribute__((address_space(1))) unsigned int*)g,
      (__attribute__((address_space(3))) unsigned int*)l, 16, 0, 0);
}

// ---- prep: A [M][K] f32 -> bf16 (same layout) ----
__global__ void k_convert_a(const float* __restrict__ a, unsigned short* __restrict__ o) {
  const size_t n8 = (size_t)M_DIM * K_DIM / 8;
  for (size_t i = (size_t)blockIdx.x * blockDim.x + threadIdx.x; i < n8;
       i += (size_t)gridDim.x * blockDim.x) {
    const f32x4* p = (const f32x4*)(a + i * 8);
    f32x4 v0 = p[0];
    f32x4 v1 = p[1];
    u16x4 r0, r1;
#pragma unroll
    for (int j = 0; j < 4; ++j) { r0[j] = f2bf(v0[j]); r1[j] = f2bf(v1[j]); }
    *(u16x4*)(o + i * 8) = r0;
    *(u16x4*)(o + i * 8 + 4) = r1;
  }
}

// ---- prep: W [K][N] f32 -> Wt [N][K] bf16 (transpose + convert) ----
__global__ void k_convert_w_t(const float* __restrict__ w, unsigned short* __restrict__ wt) {
  __shared__ float tile[64][65];
  const int bk = blockIdx.y * 64;
  const int bn = blockIdx.x * 64;
  const int t = threadIdx.x;  // 256
  const int c4 = (t & 15) * 4;
  const int r = t >> 4;
#pragma unroll
  for (int p = 0; p < 4; ++p) {
    const int row = r + p * 16;
    f32x4 v = *(const f32x4*)&w[(size_t)(bk + row) * N_DIM + bn + c4];
    tile[row][c4 + 0] = v[0];
    tile[row][c4 + 1] = v[1];
    tile[row][c4 + 2] = v[2];
    tile[row][c4 + 3] = v[3];
  }
  __syncthreads();
#pragma unroll
  for (int p = 0; p < 4; ++p) {
    const int c = r + p * 16;
    u16x4 o;
#pragma unroll
    for (int j = 0; j < 4; ++j) o[j] = f2bf(tile[c4 + j][c]);
    *(u16x4*)&wt[(size_t)(bn + c) * K_DIM + bk + c4] = o;
  }
}

// ---- main GEMM: 256x256 tile, BK=64, m201-style 8-phase / 2-K-tile schedule ----
// LDS 128KB = 2 tile-buffers x 4 regions {A0,A1,B0,B1} x 16KB.
// Tile u=2i lives in buf0, v=2i+1 in buf1 (fixed parity).
// Per phase: ds-read quadrant frags (12/4/8/0); stage 1 half-tile; barrier;
// setprio(1); 16 MFMA; setprio(0); [vmcnt at ph3/ph7]; barrier.
__global__ __launch_bounds__(512, 2) void k_gemm_8ph(
    const unsigned short* __restrict__ A, const unsigned short* __restrict__ Bt,
    const float* __restrict__ bias, float* __restrict__ C) {
  __shared__ __align__(16) unsigned short S[65536];  // 128 KB

  const int tid = threadIdx.x;
  const int lane = tid & 63;
  const int wave = tid >> 6;  // 0..7
  const int wm = wave >> 2;   // 0..1 -> 128-row block (A half)
  const int wn = wave & 3;    // 0..3 -> 64-col block
  const int fr = lane & 15;
  const int hi = lane >> 4;   // 0..3

  // T1: XCD-aware bijective swizzle. 2048 blocks, 2048%8==0.
  const int bid = blockIdx.x;
  const int swz = (bid & 7) * 256 + (bid >> 3);
  const int local = swz & 255;
  const int tm = local & 63;                     // M/256 index
  const int tn = (swz >> 8) * 4 + (local >> 6);  // N/256 index
  const int brow = tm * 256;
  const int bcol = tn * 256;

  // staging source (per-lane, pre-swizzled k; T2 involution on 8-elem granules)
  const int srow = tid >> 3;                             // 0..63
  const int skel = ((tid & 7) * 8) ^ ((srow & 7) << 3);  // swizzled k-elem
  const unsigned short* aSrc = A + (size_t)(brow + srow) * K_DIM + skel;
  const unsigned short* bSrc = Bt + (size_t)(bcol + srow) * K_DIM + skel;

  // STAGE half-tile: region r of tile tt -> buf (tt&1). LDS dest LINEAR.
#define STAGE_A(h, tt)                                                            \
  do {                                                                            \
    unsigned short* d = S + ((tt)&1) * 32768 + (h)*8192 + tid * 8;                \
    const unsigned short* g = aSrc + (size_t)((h)*128) * K_DIM + (size_t)(tt)*64; \
    gl_lds16(g, d);                                                               \
    gl_lds16(g + (size_t)64 * K_DIM, d + 4096);                                   \
  } while (0)
#define STAGE_B(h, tt)                                                            \
  do {                                                                            \
    unsigned short* d = S + ((tt)&1) * 32768 + (2 + (h)) * 8192 + tid * 8;        \
    const unsigned short* g = bSrc + (size_t)((h)*128) * K_DIM + (size_t)(tt)*64; \
    gl_lds16(g, d);                                                               \
    gl_lds16(g + (size_t)64 * K_DIM, d + 4096);                                   \
  } while (0)

  // frag-read swizzled k offsets (elements)
  const int swk0 = (hi * 8) ^ ((fr & 7) << 3);       // kk=0 granule
  const int swk1 = (32 + hi * 8) ^ ((fr & 7) << 3);  // kk=1 granule

  // loop-invariant frag base pointers (tile u -> buf0, tile v -> buf1)
  const unsigned short* Sa0 = S + wm * 8192 + fr * 64;
  const unsigned short* Sb0 = S + (2 + (wn >> 1)) * 8192 + ((wn & 1) * 64 + fr) * 64;
  const unsigned short* Sa1 = Sa0 + 32768;
  const unsigned short* Sb1 = Sb0 + 32768;

  f32x4 acc[8][4] = {};

#define BAR asm volatile("s_barrier" ::: "memory")
#define MFMA_Q(AK0, AK1, BK0, BK1, N0)                                                       \
  do {                                                                                       \
    __builtin_amdgcn_s_setprio(1);                                                           \
    _Pragma("unroll") for (int m = 0; m < 4; ++m) _Pragma("unroll") for (int n = 0; n < 2;   \
                                                                         ++n) acc[(AK0##_M) + m][N0 + n] = \
        __builtin_amdgcn_mfma_f32_16x16x32_bf16(AK0[m], BK0[N0 + n],                         \
                                                acc[(AK0##_M) + m][N0 + n], 0, 0, 0);        \
    _Pragma("unroll") for (int m = 0; m < 4; ++m) _Pragma("unroll") for (int n = 0; n < 2;   \
                                                                         ++n) acc[(AK0##_M) + m][N0 + n] = \
        __builtin_amdgcn_mfma_f32_16x16x32_bf16(AK1[m], BK1[N0 + n],                         \
                                                acc[(AK0##_M) + m][N0 + n], 0, 0, 0);        \
    __builtin_amdgcn_s_setprio(0);                                                           \
  } while (0)

  // ---- prologue: tile0 full + A0 of tile1; drain tile0 (leave 2 in flight) ----
  STAGE_A(0, 0); STAGE_A(1, 0); STAGE_B(0, 0); STAGE_B(1, 0);
  STAGE_A(0, 1);
  asm volatile("s_waitcnt vmcnt(2)" ::: "memory");
  BAR;

  for (int it = 0; it < NT / 2; ++it) {
    const int u = 2 * it;
    const int v = u + 1;
    const bool pf = (it < NT / 2 - 1);  // prefetch tiles u+2 / v+2 exist

    bf16x8 aLk0[4], aLk1[4], aHk0[4], aHk1[4], bk0[4], bk1[4];

    // ================= tile u (buf0) =================
    // -- ph0: q0 (m0-3 x n0-1) : 12 reads --
#pragma unroll
    for (int n = 0; n < 2; ++n) {
      bk0[n] = *(const bf16x8*)(Sb0 + n * 1024 + swk0);
      bk1[n] = *(const bf16x8*)(Sb0 + n * 1024 + swk1);
    }
#pragma unroll
    for (int m = 0; m < 4; ++m) {
      aLk0[m] = *(const bf16x8*)(Sa0 + m * 1024 + swk0);
      aLk1[m] = *(const bf16x8*)(Sa0 + m * 1024 + swk1);
    }
    STAGE_A(1, v);
    BAR;
    { enum { aLk0_M = 0 }; MFMA_Q(aLk0, aLk1, bk0, bk1, 0); }
    BAR;

    // -- ph1: q1 (m0-3 x n2-3) : 4 reads --
#pragma unroll
    for (int n = 2; n < 4; ++n) {
      bk0[n] = *(const bf16x8*)(Sb0 + n * 1024 + swk0);
      bk1[n] = *(const bf16x8*)(Sb0 + n * 1024 + swk1);
    }
    STAGE_B(0, v);
    BAR;
    { enum { aLk0_M = 0 }; MFMA_Q(aLk0, aLk1, bk0, bk1, 2); }
    BAR;

    // -- ph2: q2 (m4-7 x n0-1) : 8 reads --
#pragma unroll
    for (int m = 0; m < 4; ++m) {
      aHk0[m] = *(const bf16x8*)(Sa0 + (4 + m) * 1024 + swk0);
      aHk1[m] = *(const bf16x8*)(Sa0 + (4 + m) * 1024 + swk1);
    }
    STAGE_B(1, v);
    BAR;
    { enum { aHk0_M = 4 }; MFMA_Q(aHk0, aHk1, bk0, bk1, 0); }
    BAR;

    // -- ph3: q3 (m4-7 x n2-3) : 0 reads; vmcnt drains tile v --
    if (pf) STAGE_A(0, u + 2);
    BAR;
    { enum { aHk0_M = 4 }; MFMA_Q(aHk0, aHk1, bk0, bk1, 2); }
    if (pf) asm volatile("s_waitcnt vmcnt(2)" ::: "memory");
    else    asm volatile("s_waitcnt vmcnt(0)" ::: "memory");
    BAR;

    // ================= tile v (buf1) =================
    // -- ph4: q0 : 12 reads --
#pragma unroll
    for (int n = 0; n < 2; ++n) {
      bk0[n] = *(const bf16x8*)(Sb1 + n * 1024 + swk0);
      bk1[n] = *(const bf16x8*)(Sb1 + n * 1024 + swk1);
    }
#pragma unroll
    for (int m = 0; m < 4; ++m) {
      aLk0[m] = *(const bf16x8*)(Sa1 + m * 1024 + swk0);
      aLk1[m] = *(const bf16x8*)(Sa1 + m * 1024 + swk1);
    }
    if (pf) STAGE_A(1, u + 2);
    BAR;
    { enum { aLk0_M = 0 }; MFMA_Q(aLk0, aLk1, bk0, bk1, 0); }
    BAR;

    // -- ph5: q1 : 4 reads --
#pragma unroll
    for (int n = 2; n < 4; ++n) {
      bk0[n] = *(const bf16x8*)(Sb1 + n * 1024 + swk0);
      bk1[n] = *(const bf16x8*)(Sb1 + n * 1024 + swk1);
    }
    if (pf) STAGE_B(0, u + 2);
    BAR;
    { enum { aLk0_M = 0 }; MFMA_Q(aLk0, aLk1, bk0, bk1, 2); }
    BAR;

    // -- ph6: q2 : 8 reads --
#pragma unroll
    for (int m = 0; m < 4; ++m) {
      aHk0[m] = *(const bf16x8*)(Sa1 + (4 + m) * 1024 + swk0);
      aHk1[m] = *(const bf16x8*)(Sa1 + (4 + m) * 1024 + swk1);
    }
    if (pf) STAGE_B(1, u + 2);
    BAR;
    { enum { aHk0_M = 4 }; MFMA_Q(aHk0, aHk1, bk0, bk1, 0); }
    BAR;

    // -- ph7: q3 : 0 reads; stage A0 of v+2; vmcnt drains tile u+2 --
    if (pf) STAGE_A(0, v + 2);
    BAR;
    { enum { aHk0_M = 4 }; MFMA_Q(aHk0, aHk1, bk0, bk1, 2); }
    if (pf) asm volatile("s_waitcnt vmcnt(2)" ::: "memory");
    else    asm volatile("s_waitcnt vmcnt(0)" ::: "memory");
    BAR;
  }
#undef STAGE_A
#undef STAGE_B
#undef MFMA_Q
#undef BAR

  // ---- epilogue: C/D layout col = lane&15, row = (lane>>4)*4 + j ----
#pragma unroll
  for (int n = 0; n < 4; ++n) {
    const int col = bcol + wn * 64 + n * 16 + fr;
    const float bb = bias[col];
#pragma unroll
    for (int m = 0; m < 8; ++m) {
      const int row0 = brow + wm * 128 + m * 16 + hi * 4;
#pragma unroll
      for (int j = 0; j < 4; ++j)
        C[(size_t)(row0 + j) * N_DIM + col] = acc[m][n][j] + bb;
    }
  }
}

// ---- fallback (only if ws too small): fp32 LDS-tiled GEMM ----
__global__ __launch_bounds__(256) void k_gemm_f32(
    const float* __restrict__ A, const float* __restrict__ W,
    const float* __restrict__ bias, float* __restrict__ C) {
  __shared__ float As[64][17];
  __shared__ float Ws[16][64];
  const int tid = threadIdx.x;
  const int tx = tid & 15, ty = tid >> 4;
  const int brow = blockIdx.y * 64, bcol = blockIdx.x * 64;
  float acc[4][4] = {};
  for (int ks = 0; ks < K_DIM; ks += 16) {
    {
      const int m = tid >> 2, k = (tid & 3) * 4;
      f32x4 v = *(const f32x4*)&A[(size_t)(brow + m) * K_DIM + ks + k];
      As[m][k] = v[0]; As[m][k + 1] = v[1]; As[m][k + 2] = v[2]; As[m][k + 3] = v[3];
    }
    {
      const int k = tid >> 4, n = (tid & 15) * 4;
      *(f32x4*)&Ws[k][n] = *(const f32x4*)&W[(size_t)(ks + k) * N_DIM + bcol + n];
    }
    __syncthreads();
#pragma unroll
    for (int k = 0; k < 16; ++k) {
      float av[4], bv[4];
#pragma unroll
      for (int i = 0; i < 4; ++i) av[i] = As[ty * 4 + i][k];
#pragma unroll
      for (int j = 0; j < 4; ++j) bv[j] = Ws[k][tx * 4 + j];
#pragma unroll
      for (int i = 0; i < 4; ++i)
#pragma unroll
        for (int j = 0; j < 4; ++j) acc[i][j] += av[i] * bv[j];
    }
    __syncthreads();
  }
#pragma unroll
  for (int i = 0; i < 4; ++i) {
    const int row = brow + ty * 4 + i;
#pragma unroll
    for (int j = 0; j < 4; ++j) {
      const int col = bcol + tx * 4 + j;
      C[(size_t)row * N_DIM + col] = acc[i][j] + bias[col];
    }
  }
}

extern "C" void kernel_launch(void* const* d_in, const int* in_sizes, int n_in,
                              void* d_out, int out_size, void* d_ws, size_t ws_size,
                              hipStream_t stream) {
  const float* inp = (const float*)d_in[0];   // [16384, 4096]
  const float* w = (const float*)d_in[1];     // [4096, 8192]
  const float* bias = (const float*)d_in[2];  // [8192]
  float* out = (float*)d_out;                 // [16384, 8192]

  const size_t needA = (size_t)M_DIM * K_DIM * sizeof(unsigned short);  // 128 MB
  const size_t needW = (size_t)N_DIM * K_DIM * sizeof(unsigned short);  // 64 MB

  if (ws_size >= needA + needW) {
    unsigned short* Abf = (unsigned short*)d_ws;
    unsigned short* Wtb = (unsigned short*)((char*)d_ws + needA);
    k_convert_a<<<2048, 256, 0, stream>>>(inp, Abf);
    k_convert_w_t<<<dim3(N_DIM / 64, K_DIM / 64), 256, 0, stream>>>(w, Wtb);
    k_gemm_8ph<<<(M_DIM / 256) * (N_DIM / 256), 512, 0, stream>>>(Abf, Wtb, bias, out);
  } else {
    k_gemm_f32<<<dim3(N_DIM / 64, M_DIM / 64), 256, 0, stream>>>(inp, w, bias, out);
  }
}